// Round 1
// baseline (1874.965 us; speedup 1.0000x reference)
//
#include <hip/hip_runtime.h>
#include <hip/hip_bf16.h>
#include <stdint.h>

#define N_NODES 100000
#define DIM 128
#define NREL 4
#define NEDGE 500000
#define LDA 136  // 128 + 8 bf16 pad: breaks power-of-2 LDS row stride

typedef __attribute__((ext_vector_type(8))) short short8;
typedef __attribute__((ext_vector_type(4))) float f32x4;

__device__ __forceinline__ unsigned short f2bf(float f) {
  unsigned int u = __float_as_uint(f);
  u += 0x7fffu + ((u >> 16) & 1u);   // round-to-nearest-even
  return (unsigned short)(u >> 16);
}

// Build combined B matrices in MFMA-fragment order (bf16) + combined bias.
// Wt logical contents: b=0 -> (sum_r Wself_r)/4 ; b=1+r -> Wneigh_r.
// Fragment order: Wt[(((b*4+ks)*8+ct)*64+lane)*8+j] = B[k=ks*32+quad*8+j][n=ct*16+lr],
// lane = quad*16+lr. So a wave's B-frag load is one coalesced 16B/lane read.
__global__ void prep_kernel(const float* __restrict__ Ws, const float* __restrict__ Wn,
                            const float* __restrict__ bv, unsigned short* __restrict__ Wt,
                            float* __restrict__ biasc) {
  int tid = blockIdx.x * 256 + threadIdx.x;
  if (tid < 5 * DIM * DIM) {
    int b = tid / (DIM * DIM);
    int idx = tid - b * DIM * DIM;   // idx = k*DIM + n (row-major [k][n], matches W layout)
    int k = idx >> 7;
    int n = idx & 127;
    float v;
    if (b == 0)
      v = 0.25f * (Ws[idx] + Ws[DIM * DIM + idx] + Ws[2 * DIM * DIM + idx] + Ws[3 * DIM * DIM + idx]);
    else
      v = Wn[(b - 1) * DIM * DIM + idx];
    int ks = k >> 5, kq = (k >> 3) & 3, j = k & 7;
    int ct = n >> 4, lr = n & 15;
    int lane = kq * 16 + lr;
    Wt[((((b * 4 + ks) * 8) + ct) * 64 + lane) * 8 + j] = f2bf(v);
  }
  if (tid < DIM)
    biasc[tid] = 0.25f * (bv[tid] + bv[DIM + tid] + bv[2 * DIM + tid] + bv[3 * DIM + tid]);
}

// Per-(relation,node) in-degree histogram.
__global__ void count_kernel(const int* __restrict__ dst, int* __restrict__ cnt) {
  int idx = blockIdx.x * 256 + threadIdx.x;
  if (idx < NREL * NEDGE) {
    int r = idx / NEDGE;  // constant divisor -> mulhi
    atomicAdd(&cnt[(size_t)r * N_NODES + dst[idx]], 1);
  }
}

// C-tiles of 128 rows x 128 cols. A (x rows, bf16) staged once in LDS, full K=128.
// B fragments read directly from pre-swizzled global Wt (L2-resident, 160KB total).
// bi==0: write f32 out + bias. bi>0: write bf16 y slab (bi-1).
__global__ __launch_bounds__(256) void gemm_kernel(
    const float* __restrict__ x, const unsigned short* __restrict__ Wt,
    const float* __restrict__ biasc, float* __restrict__ out,
    unsigned short* __restrict__ y, long long ySlab, int bLo, int bHi) {
  __shared__ unsigned short As[128][LDA];
  int tid = threadIdx.x;
  int rowBase = blockIdx.x * 128;

  // stage A: 256 thr, each pass = 8 rows x (32 thr * float4)
  {
    int kq = (tid & 31) * 4;
    int m0 = tid >> 5;
#pragma unroll
    for (int p = 0; p < 16; ++p) {
      int m = p * 8 + m0;
      int g = rowBase + m;
      float4 v = {0.f, 0.f, 0.f, 0.f};
      if (g < N_NODES) v = *(const float4*)(x + (size_t)g * DIM + kq);
      ushort4 s;
      s.x = f2bf(v.x); s.y = f2bf(v.y); s.z = f2bf(v.z); s.w = f2bf(v.w);
      *(ushort4*)&As[m][kq] = s;
    }
  }
  __syncthreads();

  int lane = tid & 63;
  int wv = tid >> 6;       // wave -> rows wv*32 .. wv*32+31
  int quad = lane >> 4;
  int lr = lane & 15;
  const short8* Bp = (const short8*)Wt;

  float bias8[8];
#pragma unroll
  for (int ct = 0; ct < 8; ++ct) bias8[ct] = biasc[ct * 16 + lr];

  for (int bi = bLo; bi <= bHi; ++bi) {
    f32x4 zero = {0.f, 0.f, 0.f, 0.f};
    f32x4 acc[2][8];
#pragma unroll
    for (int rt = 0; rt < 2; ++rt)
#pragma unroll
      for (int ct = 0; ct < 8; ++ct) acc[rt][ct] = zero;

#pragma unroll
    for (int ks = 0; ks < 4; ++ks) {
      int k0 = ks * 32 + quad * 8;
      short8 a0 = *(const short8*)&As[wv * 32 + lr][k0];
      short8 a1 = *(const short8*)&As[wv * 32 + 16 + lr][k0];
#pragma unroll
      for (int ct = 0; ct < 8; ++ct) {
        short8 bf = Bp[((bi * 4 + ks) * 8 + ct) * 64 + lane];
        acc[0][ct] = __builtin_amdgcn_mfma_f32_16x16x32_bf16(a0, bf, acc[0][ct], 0, 0, 0);
        acc[1][ct] = __builtin_amdgcn_mfma_f32_16x16x32_bf16(a1, bf, acc[1][ct], 0, 0, 0);
      }
    }

    if (bi == 0) {
#pragma unroll
      for (int rt = 0; rt < 2; ++rt)
#pragma unroll
        for (int i = 0; i < 4; ++i) {
          int g = rowBase + wv * 32 + rt * 16 + quad * 4 + i;
          if (g < N_NODES) {
#pragma unroll
            for (int ct = 0; ct < 8; ++ct)
              out[(size_t)g * DIM + ct * 16 + lr] = acc[rt][ct][i] + bias8[ct];
          }
        }
    } else {
      unsigned short* yb = y + (long long)(bi - 1) * ySlab;
#pragma unroll
      for (int rt = 0; rt < 2; ++rt)
#pragma unroll
        for (int i = 0; i < 4; ++i) {
          int g = rowBase + wv * 32 + rt * 16 + quad * 4 + i;
          if (g < N_NODES) {
#pragma unroll
            for (int ct = 0; ct < 8; ++ct)
              yb[(size_t)g * DIM + ct * 16 + lr] = f2bf(acc[rt][ct][i]);
          }
        }
    }
  }
}

// One wave per edge: read y[src] row (bf16, 4B/lane), scale by 1/(4*max(cnt,1)),
// hardware-f32-atomic-add into out[dst] row (2 dwords/lane).
__global__ __launch_bounds__(256) void scatter_kernel(
    const unsigned short* __restrict__ yr, const int* __restrict__ srcr,
    const int* __restrict__ dstr, const int* __restrict__ cntr,
    float* __restrict__ out) {
  int lane = threadIdx.x & 63;
  int wid = blockIdx.x * 4 + (threadIdx.x >> 6);
  int stride = gridDim.x * 4;
  for (int e = wid; e < NEDGE; e += stride) {
    int s = srcr[e];
    int d = dstr[e];
    int c = cntr[d];
    float scale = 0.25f / (float)(c > 0 ? c : 1);
    const unsigned int* yp = (const unsigned int*)(yr + (size_t)s * DIM);
    unsigned int v = yp[lane];
    float f0 = __uint_as_float((v & 0xffffu) << 16) * scale;
    float f1 = __uint_as_float((v >> 16) << 16) * scale;
    float* op = out + (size_t)d * DIM + lane * 2;
    unsafeAtomicAdd(op, f0);
    unsafeAtomicAdd(op + 1, f1);
  }
}

extern "C" void kernel_launch(void* const* d_in, const int* in_sizes, int n_in,
                              void* d_out, int out_size, void* d_ws, size_t ws_size,
                              hipStream_t stream) {
  const float* x = (const float*)d_in[0];
  const int* src = (const int*)d_in[1];
  const int* dst = (const int*)d_in[2];
  const float* Wself = (const float*)d_in[3];
  const float* Wneigh = (const float*)d_in[4];
  const float* bv = (const float*)d_in[5];
  float* out = (float*)d_out;

  char* ws = (char*)d_ws;
  int* cnt = (int*)ws;                                   // R*N ints = 1,600,000 B
  size_t off = (size_t)NREL * N_NODES * sizeof(int);
  unsigned short* Wt = (unsigned short*)(ws + off);      // 5*128*128 bf16 = 163,840 B
  off += 5 * DIM * DIM * sizeof(unsigned short);
  float* biasc = (float*)(ws + off);                     // 512 B
  off += DIM * sizeof(float);
  unsigned short* y = (unsigned short*)(ws + off);       // bf16 y slabs
  long long slab = (long long)N_NODES * DIM;
  bool pathA = ws_size >= off + (size_t)NREL * (size_t)slab * sizeof(unsigned short);

  hipMemsetAsync(cnt, 0, (size_t)NREL * N_NODES * sizeof(int), stream);
  count_kernel<<<(NREL * NEDGE + 255) / 256, 256, 0, stream>>>(dst, cnt);
  prep_kernel<<<(5 * DIM * DIM + 255) / 256, 256, 0, stream>>>(Wself, Wneigh, bv, Wt, biasc);

  int gg = (N_NODES + 127) / 128;  // 782
  if (pathA) {
    // one GEMM launch computes out-init + all 4 y slabs (x staged once)
    gemm_kernel<<<gg, 256, 0, stream>>>(x, Wt, biasc, out, y, slab, 0, 4);
    for (int r = 0; r < NREL; ++r)
      scatter_kernel<<<8192, 256, 0, stream>>>(y + (size_t)r * slab, src + (size_t)r * NEDGE,
                                               dst + (size_t)r * NEDGE, cnt + (size_t)r * N_NODES, out);
  } else {
    // ws-constrained: reuse one y slab per relation (stream order serializes)
    gemm_kernel<<<gg, 256, 0, stream>>>(x, Wt, biasc, out, y, 0, 0, 0);
    for (int r = 0; r < NREL; ++r) {
      gemm_kernel<<<gg, 256, 0, stream>>>(x, Wt, biasc, out, y, 0, 1 + r, 1 + r);
      scatter_kernel<<<8192, 256, 0, stream>>>(y, src + (size_t)r * NEDGE,
                                               dst + (size_t)r * NEDGE, cnt + (size_t)r * N_NODES, out);
    }
  }
}

// Round 2
// 523.515 us; speedup vs baseline: 3.5815x; 3.5815x over previous
//
#include <hip/hip_runtime.h>
#include <hip/hip_bf16.h>
#include <stdint.h>

#define N_NODES 100000
#define DIM 128
#define NREL 4
#define NEDGE 500000
#define M_FLAT (NREL * N_NODES)   // 400000 (r,node) pairs
#define TOT_E (NREL * NEDGE)      // 2M edges
#define LDA 136                   // 128 + 8 bf16 pad

typedef __attribute__((ext_vector_type(8))) short short8;
typedef __attribute__((ext_vector_type(4))) float f32x4;

__device__ __forceinline__ unsigned short f2bf(float f) {
  unsigned int u = __float_as_uint(f);
  u += 0x7fffu + ((u >> 16) & 1u);   // RNE
  return (unsigned short)(u >> 16);
}
__device__ __forceinline__ float bflo(unsigned int v) { return __uint_as_float((v & 0xffffu) << 16); }
__device__ __forceinline__ float bfhi(unsigned int v) { return __uint_as_float((v >> 16) << 16); }

// Combined B in MFMA fragment order. b=0: (sum_r Wself_r)/4 ; b=1+r: Wneigh_r/4
// (channel-mean folded into weights). biasc = mean_r b_r.
__global__ void prep_kernel(const float* __restrict__ Ws, const float* __restrict__ Wn,
                            const float* __restrict__ bv, unsigned short* __restrict__ Wt,
                            float* __restrict__ biasc) {
  int tid = blockIdx.x * 256 + threadIdx.x;
  if (tid < 5 * DIM * DIM) {
    int b = tid / (DIM * DIM);
    int idx = tid - b * DIM * DIM;   // k*DIM + n
    int k = idx >> 7, n = idx & 127;
    float v;
    if (b == 0)
      v = 0.25f * (Ws[idx] + Ws[DIM * DIM + idx] + Ws[2 * DIM * DIM + idx] + Ws[3 * DIM * DIM + idx]);
    else
      v = 0.25f * Wn[(b - 1) * DIM * DIM + idx];
    int ks = k >> 5, kq = (k >> 3) & 3, j = k & 7;
    int ct = n >> 4, lr = n & 15;
    int lane = kq * 16 + lr;
    Wt[((((b * 4 + ks) * 8) + ct) * 64 + lane) * 8 + j] = f2bf(v);
  }
  if (tid < DIM)
    biasc[tid] = 0.25f * (bv[tid] + bv[DIM + tid] + bv[2 * DIM + tid] + bv[3 * DIM + tid]);
}

__global__ void xb_kernel(const float* __restrict__ x, unsigned short* __restrict__ xb) {
  int i = blockIdx.x * 256 + threadIdx.x;           // over 3.2M float4s
  if (i < N_NODES * DIM / 4) {
    float4 v = ((const float4*)x)[i];
    ushort4 s;
    s.x = f2bf(v.x); s.y = f2bf(v.y); s.z = f2bf(v.z); s.w = f2bf(v.w);
    ((ushort4*)xb)[i] = s;
  }
}

__global__ void count_kernel(const int* __restrict__ dst, int* __restrict__ cnt) {
  int idx = blockIdx.x * 256 + threadIdx.x;
  if (idx < TOT_E) {
    int r = idx / NEDGE;
    atomicAdd(&cnt[(size_t)r * N_NODES + dst[idx]], 1);
  }
}

// ---- 3-phase exclusive scan over cnt[M_FLAT] -> offs ----
__global__ void scan1_kernel(const int* __restrict__ cnt, int* __restrict__ offs,
                             int* __restrict__ partials) {
  __shared__ int sh[256];
  int t = threadIdx.x;
  int base = blockIdx.x * 1024 + t * 4;
  int a0 = (base + 0 < M_FLAT) ? cnt[base + 0] : 0;
  int a1 = (base + 1 < M_FLAT) ? cnt[base + 1] : 0;
  int a2 = (base + 2 < M_FLAT) ? cnt[base + 2] : 0;
  int a3 = (base + 3 < M_FLAT) ? cnt[base + 3] : 0;
  int s = a0 + a1 + a2 + a3;
  sh[t] = s;
  __syncthreads();
  for (int o = 1; o < 256; o <<= 1) {
    int v = (t >= o) ? sh[t - o] : 0;
    __syncthreads();
    sh[t] += v;
    __syncthreads();
  }
  int excl = sh[t] - s;
  if (t == 255) partials[blockIdx.x] = sh[t];
  if (base + 0 < M_FLAT) offs[base + 0] = excl;
  if (base + 1 < M_FLAT) offs[base + 1] = excl + a0;
  if (base + 2 < M_FLAT) offs[base + 2] = excl + a0 + a1;
  if (base + 3 < M_FLAT) offs[base + 3] = excl + a0 + a1 + a2;
}

__global__ void scan2_kernel(int* __restrict__ partials, int nb) {
  __shared__ int sh[512];
  int t = threadIdx.x;
  int v = (t < nb) ? partials[t] : 0;
  sh[t] = v;
  __syncthreads();
  for (int o = 1; o < 512; o <<= 1) {
    int u = (t >= o) ? sh[t - o] : 0;
    __syncthreads();
    sh[t] += u;
    __syncthreads();
  }
  if (t < nb) partials[t] = sh[t] - v;   // exclusive block offsets, in place
}

__global__ void scan3_kernel(int* __restrict__ offs, const int* __restrict__ partials,
                             int* __restrict__ cursor) {
  int i = blockIdx.x * 256 + threadIdx.x;
  if (i < M_FLAT) {
    int v = offs[i] + partials[i >> 10];
    offs[i] = v;
    cursor[i] = v;
  }
}

__global__ void fill_kernel(const int* __restrict__ src, const int* __restrict__ dst,
                            int* __restrict__ cursor, int* __restrict__ ssrc) {
  int idx = blockIdx.x * 256 + threadIdx.x;
  if (idx < TOT_E) {
    int r = idx / NEDGE;
    int pos = atomicAdd(&cursor[(size_t)r * N_NODES + dst[idx]], 1);
    ssrc[pos] = src[idx];
  }
}

// One wave per node: per relation gather xb[src] rows (4B/lane), mean in f32,
// write agg row bf16. 8-deep ILP chunks; src-index clamp keeps loads unconditional.
__global__ __launch_bounds__(256) void aggregate_kernel(
    const unsigned int* __restrict__ xb32, const int* __restrict__ ssrc,
    const int* __restrict__ offs, const int* __restrict__ cnt,
    unsigned int* __restrict__ agg32, int rLo, int rHi, int slabBase) {
  int lane = threadIdx.x & 63;
  int n = blockIdx.x * 4 + (threadIdx.x >> 6);
  if (n >= N_NODES) return;
  for (int r = rLo; r < rHi; ++r) {
    int fl = r * N_NODES + n;
    int start = offs[fl];
    int c = cnt[fl];
    int end = start + c;
    float aL = 0.f, aH = 0.f;
    for (int e = start; e < end; e += 8) {
      int m = end - e;
      int sk[8];
#pragma unroll
      for (int k = 0; k < 8; ++k) sk[k] = ssrc[e + ((k < m) ? k : 0)];
      unsigned int v[8];
#pragma unroll
      for (int k = 0; k < 8; ++k) v[k] = xb32[(size_t)sk[k] * 64 + lane];
#pragma unroll
      for (int k = 0; k < 8; ++k) {
        unsigned int u = (k < m) ? v[k] : 0u;
        aL += bflo(u);
        aH += bfhi(u);
      }
    }
    float inv = 1.0f / (float)(c > 0 ? c : 1);
    aL *= inv; aH *= inv;
    unsigned int packed = ((unsigned int)f2bf(aH) << 16) | (unsigned int)f2bf(aL);
    agg32[((size_t)(r - slabBase) * N_NODES + n) * 64 + lane] = packed;
  }
}

// K=640 GEMM: acc kept across 5 K-slabs (bi=0: x f32->bf16; bi>=1: agg slab bf16).
// accum==0: out = acc + bias ; accum==1: out += acc.
__global__ __launch_bounds__(256) void gemm_kernel(
    const float* __restrict__ x, const unsigned short* __restrict__ Wt,
    const float* __restrict__ biasc, float* __restrict__ out,
    const unsigned short* __restrict__ agg, int slabBase, int bLo, int bHi, int accum) {
  __shared__ unsigned short As[128][LDA];
  int tid = threadIdx.x;
  int rowBase = blockIdx.x * 128;
  int lane = tid & 63;
  int wv = tid >> 6;
  int quad = lane >> 4;
  int lr = lane & 15;
  const short8* Bp = (const short8*)Wt;

  float bias8[8];
#pragma unroll
  for (int ct = 0; ct < 8; ++ct) bias8[ct] = biasc[ct * 16 + lr];

  f32x4 zero = {0.f, 0.f, 0.f, 0.f};
  f32x4 acc[2][8];
#pragma unroll
  for (int rt = 0; rt < 2; ++rt)
#pragma unroll
    for (int ct = 0; ct < 8; ++ct) acc[rt][ct] = zero;

  for (int bi = bLo; bi <= bHi; ++bi) {
    if (bi > bLo) __syncthreads();   // previous MFMA reads done before restage
    if (bi == 0) {
      int kq = (tid & 31) * 4;
      int m0 = tid >> 5;
#pragma unroll
      for (int p = 0; p < 16; ++p) {
        int m = p * 8 + m0;
        int g = rowBase + m;
        float4 v = {0.f, 0.f, 0.f, 0.f};
        if (g < N_NODES) v = *(const float4*)(x + (size_t)g * DIM + kq);
        ushort4 s;
        s.x = f2bf(v.x); s.y = f2bf(v.y); s.z = f2bf(v.z); s.w = f2bf(v.w);
        *(ushort4*)&As[m][kq] = s;
      }
    } else {
      const unsigned short* as = agg + (size_t)(bi - 1 - slabBase) * N_NODES * DIM;
#pragma unroll
      for (int p = 0; p < 8; ++p) {
        int unit = p * 256 + tid;          // 2048 units of 8 bf16
        int row = unit >> 4;
        int c8 = unit & 15;
        int g = rowBase + row;
        short8 val = {0, 0, 0, 0, 0, 0, 0, 0};
        if (g < N_NODES) val = *(const short8*)(as + (size_t)g * DIM + c8 * 8);
        *(short8*)&As[row][c8 * 8] = val;
      }
    }
    __syncthreads();

#pragma unroll
    for (int ks = 0; ks < 4; ++ks) {
      int k0 = ks * 32 + quad * 8;
      short8 a0 = *(const short8*)&As[wv * 32 + lr][k0];
      short8 a1 = *(const short8*)&As[wv * 32 + 16 + lr][k0];
#pragma unroll
      for (int ct = 0; ct < 8; ++ct) {
        short8 bf = Bp[((bi * 4 + ks) * 8 + ct) * 64 + lane];
        acc[0][ct] = __builtin_amdgcn_mfma_f32_16x16x32_bf16(a0, bf, acc[0][ct], 0, 0, 0);
        acc[1][ct] = __builtin_amdgcn_mfma_f32_16x16x32_bf16(a1, bf, acc[1][ct], 0, 0, 0);
      }
    }
  }

#pragma unroll
  for (int rt = 0; rt < 2; ++rt)
#pragma unroll
    for (int i = 0; i < 4; ++i) {
      int g = rowBase + wv * 32 + rt * 16 + quad * 4 + i;
      if (g < N_NODES) {
        if (accum == 0) {
#pragma unroll
          for (int ct = 0; ct < 8; ++ct)
            out[(size_t)g * DIM + ct * 16 + lr] = acc[rt][ct][i] + bias8[ct];
        } else {
#pragma unroll
          for (int ct = 0; ct < 8; ++ct)
            out[(size_t)g * DIM + ct * 16 + lr] += acc[rt][ct][i];
        }
      }
    }
}

extern "C" void kernel_launch(void* const* d_in, const int* in_sizes, int n_in,
                              void* d_out, int out_size, void* d_ws, size_t ws_size,
                              hipStream_t stream) {
  const float* x = (const float*)d_in[0];
  const int* src = (const int*)d_in[1];
  const int* dst = (const int*)d_in[2];
  const float* Wself = (const float*)d_in[3];
  const float* Wneigh = (const float*)d_in[4];
  const float* bv = (const float*)d_in[5];
  float* out = (float*)d_out;

  char* ws = (char*)d_ws;
  size_t off = 0;
  int* cnt = (int*)(ws + off);          off += (size_t)M_FLAT * 4;        // 1.6 MB
  int* offs = (int*)(ws + off);         off += (size_t)M_FLAT * 4;        // 1.6 MB
  int* cursor = (int*)(ws + off);       off += (size_t)M_FLAT * 4;        // 1.6 MB
  int* partials = (int*)(ws + off);     off += 512 * 4;
  unsigned short* Wt = (unsigned short*)(ws + off);  off += 5 * DIM * DIM * 2;  // 160 KB
  float* biasc = (float*)(ws + off);    off += DIM * 4;
  unsigned short* xb = (unsigned short*)(ws + off);  off += (size_t)N_NODES * DIM * 2; // 25.6 MB
  int* ssrc = (int*)(ws + off);         off += (size_t)TOT_E * 4;         // 8 MB
  unsigned short* agg = (unsigned short*)(ws + off);
  size_t slabBytes = (size_t)N_NODES * DIM * 2;                            // 25.6 MB
  bool pathA = ws_size >= off + (size_t)NREL * slabBytes;

  hipMemsetAsync(cnt, 0, (size_t)M_FLAT * 4, stream);
  xb_kernel<<<(N_NODES * DIM / 4 + 255) / 256, 256, 0, stream>>>(x, xb);
  count_kernel<<<(TOT_E + 255) / 256, 256, 0, stream>>>(dst, cnt);
  prep_kernel<<<(5 * DIM * DIM + 255) / 256, 256, 0, stream>>>(Wself, Wneigh, bv, Wt, biasc);

  int nScanBlocks = (M_FLAT + 1023) / 1024;   // 391
  scan1_kernel<<<nScanBlocks, 256, 0, stream>>>(cnt, offs, partials);
  scan2_kernel<<<1, 512, 0, stream>>>(partials, nScanBlocks);
  scan3_kernel<<<(M_FLAT + 255) / 256, 256, 0, stream>>>(offs, partials, cursor);
  fill_kernel<<<(TOT_E + 255) / 256, 256, 0, stream>>>(src, dst, cursor, ssrc);

  int gAgg = (N_NODES + 3) / 4;      // 25000 blocks, wave per node
  int gGemm = (N_NODES + 127) / 128; // 782
  if (pathA) {
    aggregate_kernel<<<gAgg, 256, 0, stream>>>((const unsigned int*)xb, ssrc, offs, cnt,
                                               (unsigned int*)agg, 0, NREL, 0);
    gemm_kernel<<<gGemm, 256, 0, stream>>>(x, Wt, biasc, out, agg, 0, 0, 4, 0);
  } else {
    gemm_kernel<<<gGemm, 256, 0, stream>>>(x, Wt, biasc, out, agg, 0, 0, 0, 0);
    for (int r = 0; r < NREL; ++r) {
      aggregate_kernel<<<gAgg, 256, 0, stream>>>((const unsigned int*)xb, ssrc, offs, cnt,
                                                 (unsigned int*)agg, r, r + 1, r);
      gemm_kernel<<<gGemm, 256, 0, stream>>>(x, Wt, biasc, out, agg, r, 1 + r, 1 + r, 1);
    }
  }
}

// Round 3
// 362.928 us; speedup vs baseline: 5.1662x; 1.4425x over previous
//
#include <hip/hip_runtime.h>
#include <hip/hip_bf16.h>
#include <stdint.h>

#define N_NODES 100000
#define DIM 128
#define NREL 4
#define NEDGE 500000
#define M_FLAT (NREL * N_NODES)        // 400000 flat (r,node) slots
#define TOT_E (NREL * NEDGE)           // 2M edges
#define NBK ((M_FLAT + 2047) / 2048)   // 196 buckets of 2048 flat slots
#define CHUNK 4096                     // edges per bscatter block
#define LDA 136                        // 128 + 8 bf16 pad

typedef __attribute__((ext_vector_type(8))) short short8;
typedef __attribute__((ext_vector_type(4))) float f32x4;

__device__ __forceinline__ unsigned short f2bf(float f) {
  unsigned int u = __float_as_uint(f);
  u += 0x7fffu + ((u >> 16) & 1u);   // RNE
  return (unsigned short)(u >> 16);
}
__device__ __forceinline__ float bflo(unsigned int v) { return __uint_as_float((v & 0xffffu) << 16); }
__device__ __forceinline__ float bfhi(unsigned int v) { return __uint_as_float((v >> 16) << 16); }

// Combined B in MFMA fragment order. b=0: (sum_r Wself_r)/4 ; b=1+r: Wneigh_r/4.
__global__ void prep_kernel(const float* __restrict__ Ws, const float* __restrict__ Wn,
                            const float* __restrict__ bv, unsigned short* __restrict__ Wt,
                            float* __restrict__ biasc) {
  int tid = blockIdx.x * 256 + threadIdx.x;
  if (tid < 5 * DIM * DIM) {
    int b = tid / (DIM * DIM);
    int idx = tid - b * DIM * DIM;   // k*DIM + n
    int k = idx >> 7, n = idx & 127;
    float v;
    if (b == 0)
      v = 0.25f * (Ws[idx] + Ws[DIM * DIM + idx] + Ws[2 * DIM * DIM + idx] + Ws[3 * DIM * DIM + idx]);
    else
      v = 0.25f * Wn[(b - 1) * DIM * DIM + idx];
    int ks = k >> 5, kq = (k >> 3) & 3, j = k & 7;
    int ct = n >> 4, lr = n & 15;
    int lane = kq * 16 + lr;
    Wt[((((b * 4 + ks) * 8) + ct) * 64 + lane) * 8 + j] = f2bf(v);
  }
  if (tid < DIM)
    biasc[tid] = 0.25f * (bv[tid] + bv[DIM + tid] + bv[2 * DIM + tid] + bv[3 * DIM + tid]);
}

__global__ void xb_kernel(const float* __restrict__ x, unsigned short* __restrict__ xb) {
  int i = blockIdx.x * 256 + threadIdx.x;
  if (i < N_NODES * DIM / 4) {
    float4 v = ((const float4*)x)[i];
    ushort4 s;
    s.x = f2bf(v.x); s.y = f2bf(v.y); s.z = f2bf(v.z); s.w = f2bf(v.w);
    ((ushort4*)xb)[i] = s;
  }
}

// Bucket histogram: LDS-reduced, 196 global atomics per block.
__global__ __launch_bounds__(256) void bhist_kernel(const int* __restrict__ dst,
                                                    int* __restrict__ bcnt) {
  __shared__ int h[NBK];
  int tid = threadIdx.x;
  for (int i = tid; i < NBK; i += 256) h[i] = 0;
  __syncthreads();
  int base = blockIdx.x * 2048;
#pragma unroll
  for (int k = 0; k < 8; ++k) {
    int idx = base + k * 256 + tid;
    if (idx < TOT_E) {
      int r = idx / NEDGE;
      int fl = r * N_NODES + dst[idx];
      atomicAdd(&h[fl >> 11], 1);
    }
  }
  __syncthreads();
  for (int i = tid; i < NBK; i += 256)
    if (h[i]) atomicAdd(&bcnt[i], h[i]);
}

// Scan 196 bucket counts -> boffs[0..NBK], init bcur, set offs[M_FLAT].
__global__ void bscan_kernel(const int* __restrict__ bcnt, int* __restrict__ boffs,
                             int* __restrict__ bcur, int* __restrict__ offs) {
  __shared__ int sh[256];
  int t = threadIdx.x;
  int v = (t < NBK) ? bcnt[t] : 0;
  sh[t] = v;
  __syncthreads();
  for (int o = 1; o < 256; o <<= 1) {
    int u = (t >= o) ? sh[t - o] : 0;
    __syncthreads();
    sh[t] += u;
    __syncthreads();
  }
  int excl = sh[t] - v;
  if (t < NBK) { boffs[t] = excl; bcur[t] = excl; }
  if (t == 255) { boffs[NBK] = sh[t]; offs[M_FLAT] = sh[t]; }
}

// Local sort of a 4096-edge chunk by bucket; coalesced run-writes of packed pairs.
__global__ __launch_bounds__(256) void bscatter_kernel(
    const int* __restrict__ src, const int* __restrict__ dst,
    int* __restrict__ bcur, unsigned int* __restrict__ gpairs) {
  __shared__ unsigned int buf[CHUNK];
  __shared__ unsigned short barr[CHUNK];
  __shared__ int hist[NBK];
  __shared__ int sbase[NBK];
  __shared__ int lcur[NBK];
  __shared__ int gbase[NBK];
  __shared__ int part[256];
  int tid = threadIdx.x;
  int base = blockIdx.x * CHUNK;
  int m = TOT_E - base; if (m > CHUNK) m = CHUNK;
  for (int i = tid; i < NBK; i += 256) { hist[i] = 0; lcur[i] = 0; }
  __syncthreads();
  unsigned int pk[CHUNK / 256];
  int bk[CHUNK / 256];
#pragma unroll
  for (int k = 0; k < CHUNK / 256; ++k) {
    int i = k * 256 + tid;
    int idx = base + i;
    int b = -1; unsigned int p = 0;
    if (i < m) {
      int r = idx / NEDGE;
      int fl = r * N_NODES + dst[idx];
      b = fl >> 11;
      p = ((unsigned int)(fl & 2047) << 17) | (unsigned int)src[idx];
      atomicAdd(&hist[b], 1);
    }
    pk[k] = p; bk[k] = b;
  }
  __syncthreads();
  {
    int v = (tid < NBK) ? hist[tid] : 0;
    part[tid] = v;
    __syncthreads();
    for (int o = 1; o < 256; o <<= 1) {
      int u = (tid >= o) ? part[tid - o] : 0;
      __syncthreads();
      part[tid] += u;
      __syncthreads();
    }
    if (tid < NBK) sbase[tid] = part[tid] - v;
  }
  __syncthreads();
#pragma unroll
  for (int k = 0; k < CHUNK / 256; ++k) {
    if (bk[k] >= 0) {
      int pos = sbase[bk[k]] + atomicAdd(&lcur[bk[k]], 1);
      buf[pos] = pk[k];
      barr[pos] = (unsigned short)bk[k];
    }
  }
  __syncthreads();
  if (tid < NBK && hist[tid] > 0)
    gbase[tid] = atomicAdd(&bcur[tid], hist[tid]) - sbase[tid];
  __syncthreads();
  for (int j = tid; j < m; j += 256)
    gpairs[gbase[barr[j]] + j] = buf[j];
}

// One block per bucket: LDS count + scan -> exact CSR (offs, ssrc).
// All cursor atomics in LDS; ssrc writes land in a hot ~41KB window (L2-absorbed).
__global__ __launch_bounds__(256) void bfill_kernel(
    const unsigned int* __restrict__ gpairs, const int* __restrict__ boffs,
    int* __restrict__ offs, int* __restrict__ ssrc) {
  __shared__ int lcnt[2048];
  __shared__ int lofs[2048];
  __shared__ int lcur[2048];
  __shared__ int part[256];
  int b = blockIdx.x;
  int tid = threadIdx.x;
  int base = boffs[b];
  int cntb = boffs[b + 1] - base;
  int flBase = b << 11;
  int flCount = M_FLAT - flBase; if (flCount > 2048) flCount = 2048;
  for (int i = tid; i < 2048; i += 256) { lcnt[i] = 0; lcur[i] = 0; }
  __syncthreads();
  for (int j = tid; j < cntb; j += 256)
    atomicAdd(&lcnt[gpairs[base + j] >> 17], 1);
  __syncthreads();
  int vals[8]; int s0 = 0;
#pragma unroll
  for (int k = 0; k < 8; ++k) { vals[k] = lcnt[tid * 8 + k]; s0 += vals[k]; }
  part[tid] = s0;
  __syncthreads();
  for (int o = 1; o < 256; o <<= 1) {
    int u = (tid >= o) ? part[tid - o] : 0;
    __syncthreads();
    part[tid] += u;
    __syncthreads();
  }
  int excl = part[tid] - s0;
#pragma unroll
  for (int k = 0; k < 8; ++k) { lofs[tid * 8 + k] = excl; excl += vals[k]; }
  __syncthreads();
  for (int i = tid; i < flCount; i += 256)
    offs[flBase + i] = base + lofs[i];
  for (int j = tid; j < cntb; j += 256) {
    unsigned int p = gpairs[base + j];
    int li = p >> 17;
    int pos = atomicAdd(&lcur[li], 1);
    ssrc[base + lofs[li] + pos] = (int)(p & 0x1FFFFu);
  }
}

// One wave per node: per relation gather xb[src] rows, mean in f32, write agg bf16.
__global__ __launch_bounds__(256) void aggregate_kernel(
    const unsigned int* __restrict__ xb32, const int* __restrict__ ssrc,
    const int* __restrict__ offs, unsigned int* __restrict__ agg32,
    int rLo, int rHi, int slabBase) {
  int lane = threadIdx.x & 63;
  int n = blockIdx.x * 4 + (threadIdx.x >> 6);
  if (n >= N_NODES) return;
  for (int r = rLo; r < rHi; ++r) {
    int fl = r * N_NODES + n;
    int start = offs[fl];
    int end = offs[fl + 1];
    int c = end - start;
    float aL = 0.f, aH = 0.f;
    for (int e = start; e < end; e += 8) {
      int m = end - e;
      int sk[8];
#pragma unroll
      for (int k = 0; k < 8; ++k) sk[k] = ssrc[e + ((k < m) ? k : 0)];
      unsigned int v[8];
#pragma unroll
      for (int k = 0; k < 8; ++k) v[k] = xb32[(size_t)sk[k] * 64 + lane];
#pragma unroll
      for (int k = 0; k < 8; ++k) {
        unsigned int u = (k < m) ? v[k] : 0u;
        aL += bflo(u);
        aH += bfhi(u);
      }
    }
    float inv = 1.0f / (float)(c > 0 ? c : 1);
    aL *= inv; aH *= inv;
    unsigned int packed = ((unsigned int)f2bf(aH) << 16) | (unsigned int)f2bf(aL);
    agg32[((size_t)(r - slabBase) * N_NODES + n) * 64 + lane] = packed;
  }
}

// K-slab GEMM over bf16 A sources (bi=0: xb; bi>=1: agg slab), acc held in AGPRs.
__global__ __launch_bounds__(256) void gemm_kernel(
    const unsigned short* __restrict__ xb, const unsigned short* __restrict__ Wt,
    const float* __restrict__ biasc, float* __restrict__ out,
    const unsigned short* __restrict__ agg, int slabBase, int bLo, int bHi, int accum) {
  __shared__ unsigned short As[128][LDA];
  int tid = threadIdx.x;
  int rowBase = blockIdx.x * 128;
  int lane = tid & 63;
  int wv = tid >> 6;
  int quad = lane >> 4;
  int lr = lane & 15;
  const short8* Bp = (const short8*)Wt;

  float bias8[8];
#pragma unroll
  for (int ct = 0; ct < 8; ++ct) bias8[ct] = biasc[ct * 16 + lr];

  f32x4 zero = {0.f, 0.f, 0.f, 0.f};
  f32x4 acc[2][8];
#pragma unroll
  for (int rt = 0; rt < 2; ++rt)
#pragma unroll
    for (int ct = 0; ct < 8; ++ct) acc[rt][ct] = zero;

  for (int bi = bLo; bi <= bHi; ++bi) {
    if (bi > bLo) __syncthreads();
    const unsigned short* as =
        (bi == 0) ? xb : agg + (size_t)(bi - 1 - slabBase) * N_NODES * DIM;
#pragma unroll
    for (int p = 0; p < 8; ++p) {
      int unit = p * 256 + tid;          // 2048 units of 8 bf16
      int row = unit >> 4;
      int c8 = unit & 15;
      int g = rowBase + row;
      short8 val = {0, 0, 0, 0, 0, 0, 0, 0};
      if (g < N_NODES) val = *(const short8*)(as + (size_t)g * DIM + c8 * 8);
      *(short8*)&As[row][c8 * 8] = val;
    }
    __syncthreads();

#pragma unroll
    for (int ks = 0; ks < 4; ++ks) {
      int k0 = ks * 32 + quad * 8;
      short8 a0 = *(const short8*)&As[wv * 32 + lr][k0];
      short8 a1 = *(const short8*)&As[wv * 32 + 16 + lr][k0];
#pragma unroll
      for (int ct = 0; ct < 8; ++ct) {
        short8 bf = Bp[((bi * 4 + ks) * 8 + ct) * 64 + lane];
        acc[0][ct] = __builtin_amdgcn_mfma_f32_16x16x32_bf16(a0, bf, acc[0][ct], 0, 0, 0);
        acc[1][ct] = __builtin_amdgcn_mfma_f32_16x16x32_bf16(a1, bf, acc[1][ct], 0, 0, 0);
      }
    }
  }

#pragma unroll
  for (int rt = 0; rt < 2; ++rt)
#pragma unroll
    for (int i = 0; i < 4; ++i) {
      int g = rowBase + wv * 32 + rt * 16 + quad * 4 + i;
      if (g < N_NODES) {
        if (accum == 0) {
#pragma unroll
          for (int ct = 0; ct < 8; ++ct)
            out[(size_t)g * DIM + ct * 16 + lr] = acc[rt][ct][i] + bias8[ct];
        } else {
#pragma unroll
          for (int ct = 0; ct < 8; ++ct)
            out[(size_t)g * DIM + ct * 16 + lr] += acc[rt][ct][i];
        }
      }
    }
}

extern "C" void kernel_launch(void* const* d_in, const int* in_sizes, int n_in,
                              void* d_out, int out_size, void* d_ws, size_t ws_size,
                              hipStream_t stream) {
  const float* x = (const float*)d_in[0];
  const int* src = (const int*)d_in[1];
  const int* dst = (const int*)d_in[2];
  const float* Wself = (const float*)d_in[3];
  const float* Wneigh = (const float*)d_in[4];
  const float* bv = (const float*)d_in[5];
  float* out = (float*)d_out;

  char* ws = (char*)d_ws;
  size_t off = 0;
  int* bcnt = (int*)(ws + off);        off += 1024;
  int* boffs = (int*)(ws + off);       off += 1024;
  int* bcur = (int*)(ws + off);        off += 1024;
  unsigned short* Wt = (unsigned short*)(ws + off);  off += 5 * DIM * DIM * 2;        // 160 KB
  float* biasc = (float*)(ws + off);   off += DIM * 4;
  int* offs = (int*)(ws + off);        off += ((size_t)(M_FLAT + 1) * 4 + 15) & ~15;  // 1.6 MB
  unsigned short* xb = (unsigned short*)(ws + off);  off += (size_t)N_NODES * DIM * 2; // 25.6 MB
  unsigned int* gpairs = (unsigned int*)(ws + off);  off += (size_t)TOT_E * 4;         // 8 MB
  int* ssrc = (int*)(ws + off);        off += (size_t)TOT_E * 4;                       // 8 MB
  unsigned short* agg = (unsigned short*)(ws + off);
  size_t slabBytes = (size_t)N_NODES * DIM * 2;                                        // 25.6 MB

  int sc = 0;
  while (sc < NREL && ws_size >= off + (size_t)(sc + 1) * slabBytes) sc++;
  if (sc < 1) sc = 1;

  hipMemsetAsync(bcnt, 0, 1024, stream);
  xb_kernel<<<(N_NODES * DIM / 4 + 255) / 256, 256, 0, stream>>>(x, xb);
  prep_kernel<<<(5 * DIM * DIM + 255) / 256, 256, 0, stream>>>(Wself, Wneigh, bv, Wt, biasc);
  bhist_kernel<<<(TOT_E + 2047) / 2048, 256, 0, stream>>>(dst, bcnt);
  bscan_kernel<<<1, 256, 0, stream>>>(bcnt, boffs, bcur, offs);
  bscatter_kernel<<<(TOT_E + CHUNK - 1) / CHUNK, 256, 0, stream>>>(src, dst, bcur, gpairs);
  bfill_kernel<<<NBK, 256, 0, stream>>>(gpairs, boffs, offs, ssrc);

  int gAgg = (N_NODES + 3) / 4;       // wave per node
  int gGemm = (N_NODES + 127) / 128;  // 782
  for (int r0 = 0; r0 < NREL; r0 += sc) {
    int cr = (NREL - r0 < sc) ? (NREL - r0) : sc;
    aggregate_kernel<<<gAgg, 256, 0, stream>>>((const unsigned int*)xb, ssrc, offs,
                                               (unsigned int*)agg, r0, r0 + cr, r0);
    int bLo = (r0 == 0) ? 0 : (1 + r0);
    gemm_kernel<<<gGemm, 256, 0, stream>>>(xb, Wt, biasc, out, agg, r0, bLo, r0 + cr,
                                           (r0 == 0) ? 0 : 1);
  }
}